// Round 11
// baseline (2683.986 us; speedup 1.0000x reference)
//
#include <hip/hip_runtime.h>

// RNN: B=64, T=512, I=1024, H=1024, fp32 in/out.
// Phase 0: transpose-convert Wx/Wh -> bf16 [N][K] in ws.
// Phase 1: xproj = x @ Wx + bx + bh (bf16 MFMA, fp32 accum) -> d_out.
// Phase 2: persistent MFMA scan, 32 blocks x 512 thr = 4 clusters x 8 members.
//   cluster c: 16 batches as TWO groups of 8; phases alternate g=0/g=1.
//   While group g's tagged publish propagates (~2 phases of slack), the
//   block computes group g^1 -> consume's first tag-check is fresh.
//   Sync = tagged 8B slots {tag, 2xbf16} only. No flags, no polls, no acks.
//   SAFETY (R10 lesson): every asm load is drained by s_waitcnt vmcnt(0)
//   INSIDE the same asm statement -- no register-in-flight crosses source
//   code; all other VMEM (out/xp/hlast/bfrag) is IR, compiler-managed.
//   Overwrite safety: producer publishes tag t+2 only after consuming t+1,
//   which transitively requires every consumer finished tag t.

#define Bdim 64
#define Tdim 512
#define Idim 1024
#define Hdim 1024
#define Mdim (Bdim * Tdim)  // 32768

typedef __attribute__((ext_vector_type(8))) short bf16x8;
typedef __attribute__((ext_vector_type(4))) float f32x4;
typedef __attribute__((ext_vector_type(4))) unsigned int u32x4;

__device__ __forceinline__ float tanh_fast(float x) {
  float e = __expf(2.0f * x);
  return 1.0f - 2.0f / (e + 1.0f);
}
__device__ __forceinline__ unsigned int f2bf(float f) {
  unsigned int u = __float_as_uint(f);
  return (u + 0x7FFFu + ((u >> 16) & 1u)) >> 16;  // RNE
}
__device__ __forceinline__ unsigned int pack2(float lo, float hi) {
  return f2bf(lo) | (f2bf(hi) << 16);
}

// ---------------- Phase 0: fp32 [K][N] -> bf16 transposed [N][K] -------------
__global__ __launch_bounds__(256) void cvt_transpose(
    const float* __restrict__ src, unsigned short* __restrict__ dst) {
  __shared__ float t[32][33];
  const int bx = blockIdx.x * 32;
  const int by = blockIdx.y * 32;
  const int ty = threadIdx.x >> 3;
  const int tx = threadIdx.x & 7;
  float4 v = *(const float4*)&src[(size_t)(by + ty) * 1024 + bx + tx * 4];
  t[ty][tx * 4 + 0] = v.x; t[ty][tx * 4 + 1] = v.y;
  t[ty][tx * 4 + 2] = v.z; t[ty][tx * 4 + 3] = v.w;
  __syncthreads();
  ushort4 o;
  o.x = (unsigned short)f2bf(t[tx * 4 + 0][ty]);
  o.y = (unsigned short)f2bf(t[tx * 4 + 1][ty]);
  o.z = (unsigned short)f2bf(t[tx * 4 + 2][ty]);
  o.w = (unsigned short)f2bf(t[tx * 4 + 3][ty]);
  *(ushort4*)&dst[(size_t)(bx + ty) * 1024 + by + tx * 4] = o;
}

// ---------------- Phase 1: bf16 MFMA GEMM, 128x128 tile, BK=32 ---------------
__global__ __launch_bounds__(256) void xg_mfma(
    const float* __restrict__ X,            // [M][K] fp32
    const unsigned short* __restrict__ WxT, // [N][K] bf16
    const float* __restrict__ bx, const float* __restrict__ bh,
    float* __restrict__ C) {                // [M][N] fp32
  __shared__ char sAB[16384] __attribute__((aligned(16)));
  char* sA = sAB;
  char* sB = sAB + 8192;
  const int tid = threadIdx.x;
  const int m0 = blockIdx.y * 128;
  const int n0 = blockIdx.x * 128;
  const int w = tid >> 6, l = tid & 63;
  const int wm = (w >> 1) * 64, wn = (w & 1) * 64;
  const int r2 = tid >> 1, kh = tid & 1;

  f32x4 acc[4][4];
#pragma unroll
  for (int i = 0; i < 4; ++i)
#pragma unroll
    for (int j = 0; j < 4; ++j) acc[i][j] = (f32x4){0.f, 0.f, 0.f, 0.f};

  for (int k0 = 0; k0 < Idim; k0 += 32) {
    const float* xa = &X[(size_t)(m0 + r2) * Idim + k0 + kh * 16];
    float4 a0 = *(const float4*)(xa + 0), a1 = *(const float4*)(xa + 4);
    float4 a2 = *(const float4*)(xa + 8), a3 = *(const float4*)(xa + 12);
    const char* wb = (const char*)&WxT[(size_t)(n0 + r2) * Idim + k0 + kh * 16];
    u32x4 b0 = *(const u32x4*)wb;
    u32x4 b1 = *(const u32x4*)(wb + 16);
    __syncthreads();
    u32x4 pa0 = {pack2(a0.x, a0.y), pack2(a0.z, a0.w),
                 pack2(a1.x, a1.y), pack2(a1.z, a1.w)};
    u32x4 pa1 = {pack2(a2.x, a2.y), pack2(a2.z, a2.w),
                 pack2(a3.x, a3.y), pack2(a3.z, a3.w)};
    const int sw = (r2 & 7) << 4;
    const int rb = r2 * 64 + kh * 32;
    *(u32x4*)(sA + ((rb + 0) ^ sw)) = pa0;
    *(u32x4*)(sA + ((rb + 16) ^ sw)) = pa1;
    *(u32x4*)(sB + ((rb + 0) ^ sw)) = b0;
    *(u32x4*)(sB + ((rb + 16) ^ sw)) = b1;
    __syncthreads();
    bf16x8 af[4], bf[4];
#pragma unroll
    for (int i = 0; i < 4; ++i) {
      int ra = wm + i * 16 + (l & 15);
      af[i] = *(const bf16x8*)(sA + ((ra * 64 + (l >> 4) * 16) ^ ((ra & 7) << 4)));
      int rn = wn + i * 16 + (l & 15);
      bf[i] = *(const bf16x8*)(sB + ((rn * 64 + (l >> 4) * 16) ^ ((rn & 7) << 4)));
    }
#pragma unroll
    for (int i = 0; i < 4; ++i)
#pragma unroll
      for (int j = 0; j < 4; ++j)
        acc[i][j] = __builtin_amdgcn_mfma_f32_16x16x32_bf16(af[i], bf[j],
                                                            acc[i][j], 0, 0, 0);
  }
  float bias[4];
#pragma unroll
  for (int j = 0; j < 4; ++j) {
    int cc = n0 + wn + j * 16 + (l & 15);
    bias[j] = bx[cc] + bh[cc];
  }
#pragma unroll
  for (int i = 0; i < 4; ++i) {
    int rbase = m0 + wm + i * 16 + (l >> 4) * 4;
#pragma unroll
    for (int j = 0; j < 4; ++j) {
      int cc = n0 + wn + j * 16 + (l & 15);
#pragma unroll
      for (int r = 0; r < 4; ++r)
        C[(size_t)(rbase + r) * Hdim + cc] = acc[i][j][r] + bias[j];
    }
  }
}

// ---------------- Phase 2: persistent MFMA scan, 2-chain pipeline ------------
// hbuf slots (8B {payload lo, tag hi}): c*16384 + g*8192 + par*4096 + b*512 + p
__global__ __launch_bounds__(512, 2) void rnn_scan(
    const unsigned short* __restrict__ WhT,  // [N=1024][K=1024] bf16
    float* __restrict__ out,                 // [B][T][H]: xproj in, h out
    float* __restrict__ hlast,               // [B][H]
    unsigned long long* hbuf) {              // ws: 512 KB tagged slots
  const int bid = blockIdx.x;
  const int c = bid & 3;   // cluster: batches c*16..+16 (2 groups of 8)
  const int m = bid >> 2;  // member: cols m*128..+128
  const int tid = threadIdx.x;
  const int w = tid >> 6;  // wave: k-slice w*128..+128; finisher batch = w
  const int l = tid & 63;
  const int n0 = m * 128;

  __shared__ char smem[16384 + 33792] __attribute__((aligned(16)));
  char* smh = smem;          // h tile [8][2048B] swizzled (shared by groups)
  char* smp = smem + 16384;  // partials [8w][8nt][33][16B] (shared by groups)

  // B-frags: IR loads (compiler-managed waits; R5-R9-proven mix)
  bf16x8 bfrag[32];
  {
    const int kb = (w << 7) + ((l >> 4) << 3);
    const int col = n0 + (l & 15);
#pragma unroll
    for (int nt = 0; nt < 8; ++nt)
#pragma unroll
      for (int kt = 0; kt < 4; ++kt)
        bfrag[nt * 4 + kt] =
            *(const bf16x8*)&WhT[(size_t)(col + nt * 16) * 1024 + kb + kt * 32];
  }

  const int c0 = l * 2;  // col pair this thread finishes (within member m)
  const size_t obase0 =
      (size_t)(c * 16 + 0 + w) * ((size_t)Tdim * Hdim) + n0 + c0;
  const size_t obase1 =
      (size_t)(c * 16 + 8 + w) * ((size_t)Tdim * Hdim) + n0 + c0;
  float2 xp0 = *(const float2*)&out[obase0];
  float2 xp1 = *(const float2*)&out[obase1];

  const int nt0 = c0 >> 4;
  const int lane0 = ((w >> 2) << 4) | (c0 & 15);
  const int regb = (w & 3) * 4;

  auto step = [&](const int g, const int t, float2& xp, const size_t obase) {
    float sum0 = 0.f, sum1 = 0.f;
    if (t > 0) {
      // ---- consume: self-contained {load+drain} asm, tag check, retry ----
      const char* src = (const char*)hbuf +
          (((size_t)c * 16384 + (size_t)g * 8192 + (size_t)(t & 1) * 4096)
           << 3) + (size_t)tid * 64;
      u32x4 vs0, vs1, vs2, vs3;
      asm volatile(
          "global_load_dwordx4 %0, %4, off sc0 sc1\n\t"
          "global_load_dwordx4 %1, %4, off offset:16 sc0 sc1\n\t"
          "global_load_dwordx4 %2, %4, off offset:32 sc0 sc1\n\t"
          "global_load_dwordx4 %3, %4, off offset:48 sc0 sc1\n\t"
          "s_waitcnt vmcnt(0)"
          : "=&v"(vs0), "=&v"(vs1), "=&v"(vs2), "=&v"(vs3)
          : "v"(src) : "memory");
      __builtin_amdgcn_sched_barrier(0);
      const unsigned int tgt = (unsigned int)t;
      bool ok = vs0.y >= tgt && vs0.w >= tgt && vs1.y >= tgt && vs1.w >= tgt &&
                vs2.y >= tgt && vs2.w >= tgt && vs3.y >= tgt && vs3.w >= tgt;
      while (__builtin_expect(!ok, 0)) {  // rare: 2-phase slack covers skew
        __builtin_amdgcn_s_sleep(1);
        asm volatile(
            "global_load_dwordx4 %0, %4, off sc0 sc1\n\t"
            "global_load_dwordx4 %1, %4, off offset:16 sc0 sc1\n\t"
            "global_load_dwordx4 %2, %4, off offset:32 sc0 sc1\n\t"
            "global_load_dwordx4 %3, %4, off offset:48 sc0 sc1\n\t"
            "s_waitcnt vmcnt(0)"
            : "=&v"(vs0), "=&v"(vs1), "=&v"(vs2), "=&v"(vs3)
            : "v"(src) : "memory");
        __builtin_amdgcn_sched_barrier(0);
        ok = vs0.y >= tgt && vs0.w >= tgt && vs1.y >= tgt && vs1.w >= tgt &&
             vs2.y >= tgt && vs2.w >= tgt && vs3.y >= tgt && vs3.w >= tgt;
      }
      // payload -> swizzled LDS (wave w stages batch-row w: l*32 bytes)
      const int bb = w * 2048 + l * 32;
      const int swz = w << 4;
      *(uint2*)(smh + ((bb + 0) ^ swz)) = make_uint2(vs0.x, vs0.z);
      *(uint2*)(smh + ((bb + 8) ^ swz)) = make_uint2(vs1.x, vs1.z);
      *(uint2*)(smh + ((bb + 16) ^ swz)) = make_uint2(vs2.x, vs2.z);
      *(uint2*)(smh + ((bb + 24) ^ swz)) = make_uint2(vs3.x, vs3.z);
      asm volatile("s_waitcnt lgkmcnt(0)" ::: "memory");
      __builtin_amdgcn_s_barrier();  // #B: tile staged
      asm volatile("" ::: "memory");
      // ---- MFMA: 8 batches x 128 cols, k-slice w*128..+128 ----
      const int arow = l & 7;
      const int ab = arow * 2048 + (w << 8) + ((l >> 4) << 4);
      const int sw2 = arow << 4;
      bf16x8 af0 = *(const bf16x8*)(smh + ((ab + 0) ^ sw2));
      bf16x8 af1 = *(const bf16x8*)(smh + ((ab + 64) ^ sw2));
      bf16x8 af2 = *(const bf16x8*)(smh + ((ab + 128) ^ sw2));
      bf16x8 af3 = *(const bf16x8*)(smh + ((ab + 192) ^ sw2));
#pragma unroll
      for (int nt = 0; nt < 8; ++nt) {
        f32x4 a = {0.f, 0.f, 0.f, 0.f};
        a = __builtin_amdgcn_mfma_f32_16x16x32_bf16(af0, bfrag[nt * 4 + 0], a, 0, 0, 0);
        a = __builtin_amdgcn_mfma_f32_16x16x32_bf16(af1, bfrag[nt * 4 + 1], a, 0, 0, 0);
        a = __builtin_amdgcn_mfma_f32_16x16x32_bf16(af2, bfrag[nt * 4 + 2], a, 0, 0, 0);
        a = __builtin_amdgcn_mfma_f32_16x16x32_bf16(af3, bfrag[nt * 4 + 3], a, 0, 0, 0);
        if (l < 32)  // lanes 32-63 hold duplicate batch rows: discard
          *(f32x4*)(smp + (((w * 8 + nt) * 33 + l) << 4)) = a;
      }
      asm volatile("s_waitcnt lgkmcnt(0)" ::: "memory");
      __builtin_amdgcn_s_barrier();  // #P: partials visible
      asm volatile("" ::: "memory");
#pragma unroll
      for (int w8 = 0; w8 < 8; ++w8) {
        const char* p = smp + (((w8 * 8 + nt0) * 33 + lane0) << 4) + regb;
        sum0 += *(const float*)p;
        sum1 += *(const float*)(p + 16);
      }
    }
    float h0 = tanh_fast(xp.x + sum0);
    float h1 = tanh_fast(xp.y + sum1);
    // ---- publish tagged slot (only producer-side action; no ack) ----
    {
      unsigned long long* pubp = hbuf + (size_t)c * 16384 + (size_t)g * 8192 +
                                 (size_t)((t + 1) & 1) * 4096 +
                                 (size_t)w * 512 + (size_t)m * 64 + l;
      unsigned long long pvv =
          ((unsigned long long)(unsigned int)(t + 1) << 32) |
          (unsigned long long)pack2(h0, h1);
      asm volatile("global_store_dwordx2 %0, %1, off sc0 sc1"
                   :: "v"(pubp), "v"(pvv) : "memory");
    }
    // ---- IR epilogue (compiler-managed): out store, xp load / hlast ----
    *(float2*)&out[obase + (size_t)t * Hdim] = make_float2(h0, h1);
    if (t < Tdim - 1) {
      xp = *(const float2*)&out[obase + (size_t)(t + 1) * Hdim];
    } else {
      *(float2*)&hlast[(size_t)(c * 16 + g * 8 + w) * Hdim + n0 + c0] =
          make_float2(h0, h1);
    }
  };

  for (int t = 0; t < Tdim; ++t) {
    step(0, t, xp0, obase0);
    step(1, t, xp1, obase1);
  }
}

extern "C" void kernel_launch(void* const* d_in, const int* in_sizes, int n_in,
                              void* d_out, int out_size, void* d_ws,
                              size_t ws_size, hipStream_t stream) {
  const float* x  = (const float*)d_in[0];
  const float* Wx = (const float*)d_in[1];
  const float* bx = (const float*)d_in[2];
  const float* Wh = (const float*)d_in[3];
  const float* bh = (const float*)d_in[4];
  float* out = (float*)d_out;
  float* hlast = out + (size_t)Bdim * Tdim * Hdim;
  unsigned long long* hbuf = (unsigned long long*)d_ws;            // 512 KB
  unsigned short* WxT = (unsigned short*)((char*)d_ws + 524288);   // 2 MB
  unsigned short* WhT = (unsigned short*)((char*)d_ws + 524288 + 2097152);

  // clear tags each launch (ws is NOT re-poisoned between graph replays)
  hipMemsetAsync(d_ws, 0, 524288, stream);

  dim3 gt(32, 32);
  cvt_transpose<<<gt, dim3(256), 0, stream>>>(Wx, WxT);
  cvt_transpose<<<gt, dim3(256), 0, stream>>>(Wh, WhT);
  xg_mfma<<<dim3(Hdim / 128, Mdim / 128), dim3(256), 0, stream>>>(x, WxT, bx,
                                                                  bh, out);
  rnn_scan<<<dim3(32), dim3(512), 0, stream>>>(WhT, out, hlast, hbuf);
}